// Round 3
// baseline (191.174 us; speedup 1.0000x reference)
//
#include <hip/hip_runtime.h>
#include <stdint.h>

typedef __attribute__((ext_vector_type(8))) short short8;
typedef __attribute__((ext_vector_type(4))) float f32x4;

__device__ __forceinline__ unsigned short f2bf(float f) {
  unsigned int u = __builtin_bit_cast(unsigned int, f);
  u += 0x7FFFu + ((u >> 16) & 1u);   // RNE
  return (unsigned short)(u >> 16);
}

#define GLD_LDS16(gp, lp) \
  __builtin_amdgcn_global_load_lds((const __attribute__((address_space(1))) void*)(gp), \
                                   (__attribute__((address_space(3))) void*)(lp), 16, 0, 0)

// ---------------- fp32 -> bf16 convert (optionally pre-scale q-rows of Wqkv by 1/8) ----
__global__ __launch_bounds__(256) void cvt_bf16_kernel(const float* __restrict__ src,
    unsigned short* __restrict__ dst, int n8, int qkvmode) {
  int i = blockIdx.x * 256 + threadIdx.x;
  if (i >= n8) return;
  const float4* s4 = (const float4*)src;
  float4 a = s4[i * 2], b = s4[i * 2 + 1];
  float scale = 1.0f;
  if (qkvmode) {
    int row = (i * 8) >> 10;                 // K = 1024 per row
    if (((row >> 6) % 3) == 0) scale = 0.125f;  // q rows: fold 1/sqrt(64), exact (pow2)
  }
  uint4 o;
  o.x = (unsigned)f2bf(a.x * scale) | ((unsigned)f2bf(a.y * scale) << 16);
  o.y = (unsigned)f2bf(a.z * scale) | ((unsigned)f2bf(a.w * scale) << 16);
  o.z = (unsigned)f2bf(b.x * scale) | ((unsigned)f2bf(b.y * scale) << 16);
  o.w = (unsigned)f2bf(b.z * scale) | ((unsigned)f2bf(b.w * scale) << 16);
  *(uint4*)(dst + (size_t)i * 8) = o;
}

// ---------------- V transpose: [bh][s][64] -> [bh][64][4096], 64x64 LDS tiles ----------
__global__ __launch_bounds__(256) void vtrans_kernel(const unsigned short* __restrict__ v,
                                                     unsigned short* __restrict__ vt) {
  __shared__ unsigned short T[64 * 66];     // pad 66: write/read <=2-way banks
  int bid = blockIdx.x;                     // 2048 = 32 bh * 64 s-tiles
  int st = bid & 63, bh = bid >> 6;
  int s0 = st * 64;
  int t = threadIdx.x;
  int row = t >> 2, c0 = (t & 3) * 16;
  const unsigned short* src = v + ((size_t)bh * 4096 + s0 + row) * 64 + c0;
  short8 a0 = *(const short8*)src;
  short8 a1 = *(const short8*)(src + 8);
  #pragma unroll
  for (int j = 0; j < 8; ++j) {
    T[row * 66 + c0 + j]     = (unsigned short)a0[j];
    T[row * 66 + c0 + 8 + j] = (unsigned short)a1[j];
  }
  __syncthreads();
  int d = t >> 2, k0 = (t & 3) * 16;
  short8 o0, o1;
  #pragma unroll
  for (int j = 0; j < 8; ++j) {
    o0[j] = (short)T[(k0 + j) * 66 + d];
    o1[j] = (short)T[(k0 + 8 + j) * 66 + d];
  }
  unsigned short* dst = vt + ((size_t)bh * 64 + d) * 4096 + s0 + k0;
  *(short8*)dst = o0;
  *(short8*)(dst + 8) = o1;
}

// ---------------- 128x128-tile bf16 GEMM, C = A @ B^T (+bias), m97 structure ----------
// EPI 0: scatter into q/k/v [B][H][S][64] bf16   EPI 1: fp32 out [M][N]
template<int EPI>
__global__ __launch_bounds__(256, 2) void gemm_bt(
    const unsigned short* __restrict__ A, const unsigned short* __restrict__ Bw,
    const float* __restrict__ bias, void* o0, void* o1, void* o2,
    int M, int N, int K, int nbc)
{
  __shared__ __align__(16) unsigned short Asm[128 * 64];
  __shared__ __align__(16) unsigned short Bsm[128 * 64];
  int chunk = gridDim.x >> 3;                       // XCD-aware swizzle (grid % 8 == 0)
  int bid = (blockIdx.x & 7) * chunk + (blockIdx.x >> 3);
  int bc = bid % nbc, br = bid / nbc;
  int tid = threadIdx.x;
  int lane = tid & 63, w = tid >> 6;
  int l16 = lane & 15, g = lane >> 4;
  int wr = w >> 1, wc = w & 1;
  f32x4 acc[4][4];
  #pragma unroll
  for (int i = 0; i < 4; i++)
    #pragma unroll
    for (int j = 0; j < 4; j++) acc[i][j] = (f32x4){0.f, 0.f, 0.f, 0.f};

  const int nkt = K >> 6;
  for (int kt = 0; kt < nkt; ++kt) {
    __syncthreads();
    #pragma unroll
    for (int r = 0; r < 4; ++r) {
      int idx = tid + 256 * r;            // lane-contiguous per wave (gload_lds linear dest)
      int row = idx >> 3, s = idx & 7;
      int gofs = ((s ^ (row & 7)) << 3) + (kt << 6);   // pre-swizzled global source
      GLD_LDS16(A + (size_t)(br * 128 + row) * K + gofs, &Asm[idx << 3]);
      GLD_LDS16(Bw + (size_t)(bc * 128 + row) * K + gofs, &Bsm[idx << 3]);
    }
    __syncthreads();
    #pragma unroll
    for (int kk = 0; kk < 2; ++kk) {
      short8 af[4], bf[4];
      #pragma unroll
      for (int i = 0; i < 4; i++) {
        int rowa = wr * 64 + i * 16 + l16;
        af[i] = *(const short8*)&Asm[(rowa << 6) + ((((kk << 2) + g) ^ (rowa & 7)) << 3)];
        int rowb = wc * 64 + i * 16 + l16;
        bf[i] = *(const short8*)&Bsm[(rowb << 6) + ((((kk << 2) + g) ^ (rowb & 7)) << 3)];
      }
      __builtin_amdgcn_s_setprio(1);
      #pragma unroll
      for (int i = 0; i < 4; i++)
        #pragma unroll
        for (int j = 0; j < 4; j++)
          acc[i][j] = __builtin_amdgcn_mfma_f32_16x16x32_bf16(af[i], bf[j], acc[i][j], 0, 0, 0);
      __builtin_amdgcn_s_setprio(0);
    }
  }
  // epilogue: D row = g*4+jj, col = l16 (m89-verified layout)
  #pragma unroll
  for (int i = 0; i < 4; i++) {
    #pragma unroll
    for (int j = 0; j < 4; j++) {
      int n = bc * 128 + wc * 64 + j * 16 + l16;
      int m0 = br * 128 + wr * 64 + i * 16 + g * 4;
      if (EPI == 0) {
        int t = (n >> 6) % 3;
        float bval = bias[n]; if (t == 0) bval *= 0.125f;
        unsigned short* dst = (unsigned short*)(t == 0 ? o0 : (t == 1 ? o1 : o2));
        int hh = n / 192, e = n & 63;
        #pragma unroll
        for (int jj = 0; jj < 4; jj++) {
          int m = m0 + jj;
          int bb = m >> 12, sq = m & 4095;   // S = 4096
          dst[((((size_t)(bb * 16 + hh) << 12) + sq) << 6) + e] = f2bf(acc[i][j][jj] + bval);
        }
      } else {
        float* o = (float*)o0;
        float bval = bias[n];
        #pragma unroll
        for (int jj = 0; jj < 4; jj++)
          o[(size_t)(m0 + jj) * N + n] = acc[i][j][jj] + bval;
      }
    }
  }
}

// ---------------- banded flash attention ------------------------------------------------
// grid: (S/64) * B*H blocks; 4 waves/block, wave owns 16 query rows.
// K staged [key][d], V^T staged [d][key], both via global_load_lds, double-buffered.
__global__ __launch_bounds__(256, 3) void attn_kernel(
    const unsigned short* __restrict__ qb, const unsigned short* __restrict__ kb,
    const unsigned short* __restrict__ vtb, const int* __restrict__ pmask,
    unsigned short* __restrict__ ctxb)
{
  const int S = 4096, HD = 64, WIN = 256;
  const float NEG = -1e38f;
  __shared__ __align__(16) unsigned short Ks[2][64 * 64];
  __shared__ __align__(16) unsigned short Vts[2][64 * 64];
  __shared__ __align__(16) unsigned short Ps[4][16 * 72];   // per-wave P, row pad 72

  int bid0 = blockIdx.x;
  int bid = (bid0 & 7) * (gridDim.x >> 3) + (bid0 >> 3);   // XCD swizzle: qt-neighbors same L2
  int qt = bid & 63;           // S/64 tiles
  int bh = bid >> 6;
  int b = bh >> 4, h = bh & 15;

  const unsigned short* Q  = qb + (size_t)bh * S * HD;
  const unsigned short* Kg = kb + (size_t)bh * S * HD;
  const unsigned short* Vt = vtb + (size_t)bh * HD * S;
  const int* pmrow = pmask + (size_t)b * S;

  int tid = threadIdx.x;
  int lane = tid & 63, w = tid >> 6;
  int l16 = lane & 15, g = lane >> 4;

  int q0 = qt * 64;
  int qw = q0 + w * 16;

  short8 qf[2];
  #pragma unroll
  for (int hh = 0; hh < 2; ++hh)
    qf[hh] = *(const short8*)&Q[(size_t)(qw + l16) * HD + hh * 32 + g * 8];

  f32x4 ctx[4];
  #pragma unroll
  for (int dt = 0; dt < 4; ++dt) ctx[dt] = (f32x4){0.f, 0.f, 0.f, 0.f};
  float mrun[4] = {-1e30f, -1e30f, -1e30f, -1e30f};
  float lrun[4] = {0.f, 0.f, 0.f, 0.f};

  int kt0 = (q0 - WIN) >> 6; if (kt0 < 0) kt0 = 0;
  int kt1 = (q0 + 63 + WIN) >> 6; if (kt1 > 63) kt1 = 63;
  int nt = kt1 - kt0 + 1;

#define STAGE(BUF, KT) do {                                                       \
    int kb_ = (KT) * 64;                                                          \
    _Pragma("unroll")                                                             \
    for (int r_ = 0; r_ < 2; ++r_) {                                              \
      int idx_ = tid + 256 * r_;                                                  \
      int row_ = idx_ >> 3, s_ = idx_ & 7;                                        \
      int c_ = (s_ ^ (row_ & 7)) << 3;                                            \
      GLD_LDS16(Kg + (size_t)(kb_ + row_) * HD + c_, &Ks[BUF][idx_ << 3]);        \
      GLD_LDS16(Vt + (size_t)row_ * S + kb_ + c_, &Vts[BUF][idx_ << 3]);          \
    }                                                                             \
  } while (0)

  STAGE(0, kt0);
  asm volatile("s_waitcnt vmcnt(0)" ::: "memory");
  __syncthreads();

  int cur = 0;
  for (int it = 0; it < nt; ++it) {
    int kbase = (kt0 + it) * 64;
    if (it + 1 < nt) STAGE(cur ^ 1, kt0 + it + 1);

    // padding-mask bias, issued early so latency hides under QK^T
    float kbv[4];
    #pragma unroll
    for (int k4 = 0; k4 < 4; ++k4)
      kbv[k4] = (pmrow[kbase + k4 * 16 + l16] != 0) ? 0.f : NEG;

    // QK^T : S[q = g*4+jj][key = 16*k4 + l16]  (q pre-scaled by 1/8)
    f32x4 sc[4];
    __builtin_amdgcn_s_setprio(1);
    #pragma unroll
    for (int k4 = 0; k4 < 4; ++k4) {
      int krow = k4 * 16 + l16;
      f32x4 s = (f32x4){0.f, 0.f, 0.f, 0.f};
      short8 kf0 = *(const short8*)&Ks[cur][(krow << 6) + ((g ^ (l16 & 7)) << 3)];
      s = __builtin_amdgcn_mfma_f32_16x16x32_bf16(qf[0], kf0, s, 0, 0, 0);
      short8 kf1 = *(const short8*)&Ks[cur][(krow << 6) + (((4 + g) ^ (l16 & 7)) << 3)];
      s = __builtin_amdgcn_mfma_f32_16x16x32_bf16(qf[1], kf1, s, 0, 0, 0);
      sc[k4] = s;
    }
    __builtin_amdgcn_s_setprio(0);

    // band + padding mask (additive; exp underflow gives exact 0)
    #pragma unroll
    for (int k4 = 0; k4 < 4; ++k4) {
      int kg = kbase + k4 * 16 + l16;
      #pragma unroll
      for (int jj = 0; jj < 4; ++jj) {
        int dq = kg - (qw + g * 4 + jj) + WIN;      // in [0, 2*WIN] iff in band
        float sv = sc[k4][jj] + kbv[k4];
        sc[k4][jj] = ((unsigned)dq <= 2u * WIN) ? sv : NEG;
      }
    }
    // online softmax per query row (reduce across the 16 key-lanes)
    float scl[4];
    #pragma unroll
    for (int jj = 0; jj < 4; ++jj) {
      float tm = fmaxf(fmaxf(sc[0][jj], sc[1][jj]), fmaxf(sc[2][jj], sc[3][jj]));
      #pragma unroll
      for (int mk = 1; mk < 16; mk <<= 1) tm = fmaxf(tm, __shfl_xor(tm, mk));
      float mn = fmaxf(fmaxf(mrun[jj], tm), -1e30f);   // floor: masked rows stay exact-0
      float sfac = __expf(mrun[jj] - mn);
      float ps = 0.f;
      #pragma unroll
      for (int k4 = 0; k4 < 4; ++k4) {
        float p = __expf(sc[k4][jj] - mn);             // masked -> underflow -> 0
        ps += p;
        Ps[w][(g * 4 + jj) * 72 + k4 * 16 + l16] = f2bf(p);
      }
      #pragma unroll
      for (int mk = 1; mk < 16; mk <<= 1) ps += __shfl_xor(ps, mk);
      lrun[jj] = lrun[jj] * sfac + ps;
      mrun[jj] = mn;
      scl[jj] = sfac;
    }
    #pragma unroll
    for (int dt = 0; dt < 4; ++dt) {
      f32x4 c = ctx[dt];
      c[0] *= scl[0]; c[1] *= scl[1]; c[2] *= scl[2]; c[3] *= scl[3];
      ctx[dt] = c;
    }
    asm volatile("s_waitcnt lgkmcnt(0)" ::: "memory");  // P writes visible wave-wide
    __builtin_amdgcn_sched_barrier(0);
    // PV : ctx[q][d] += P[16q x 64keys] @ Vt[64d x 64keys]
    short8 pf0 = *(const short8*)&Ps[w][l16 * 72 + g * 8];
    short8 pf1 = *(const short8*)&Ps[w][l16 * 72 + 32 + g * 8];
    __builtin_amdgcn_s_setprio(1);
    #pragma unroll
    for (int dt = 0; dt < 4; ++dt) {
      int drow = dt * 16 + l16;
      short8 vf0 = *(const short8*)&Vts[cur][(drow << 6) + ((g ^ (drow & 7)) << 3)];
      ctx[dt] = __builtin_amdgcn_mfma_f32_16x16x32_bf16(pf0, vf0, ctx[dt], 0, 0, 0);
      short8 vf1 = *(const short8*)&Vts[cur][(drow << 6) + (((4 + g) ^ (drow & 7)) << 3)];
      ctx[dt] = __builtin_amdgcn_mfma_f32_16x16x32_bf16(pf1, vf1, ctx[dt], 0, 0, 0);
    }
    __builtin_amdgcn_s_setprio(0);

    if (it + 1 < nt) {
      asm volatile("s_waitcnt vmcnt(0)" ::: "memory");  // next tile landed (issued pre-compute)
      __syncthreads();                                   // also: all waves done with cur
      cur ^= 1;
    }
  }
#undef STAGE

  // write ctx as bf16 in [B][S][H*64] (A-layout for the output GEMM)
  #pragma unroll
  for (int jj = 0; jj < 4; ++jj) {
    float rc = (lrun[jj] > 0.f) ? (1.f / lrun[jj]) : 0.f;
    int qrow = qw + g * 4 + jj;
    size_t base = ((size_t)b * S + qrow) * 1024 + h * 64;
    #pragma unroll
    for (int dt = 0; dt < 4; ++dt)
      ctxb[base + dt * 16 + l16] = f2bf(ctx[dt][jj] * rc);
  }
}

// ---------------- launch ----------------------------------------------------------------
extern "C" void kernel_launch(void* const* d_in, const int* in_sizes, int n_in,
                              void* d_out, int out_size, void* d_ws, size_t ws_size,
                              hipStream_t stream) {
  const float* x     = (const float*)d_in[0];
  const int*   pmask = (const int*)d_in[1];
  const float* Wqkv  = (const float*)d_in[2];
  const float* bqkv  = (const float*)d_in[3];
  const float* Wo    = (const float*)d_in[4];
  const float* bo    = (const float*)d_in[5];

  // Memory map (56MB of ws + d_out doubling as q/k scratch):
  //   ws:    xb@0 (16MB, dead after QKV GEMM -> reused as vtb) | Wqkvb@16MB (6MB) |
  //          Wob@22MB (2MB) | vbuf@24MB (16MB) | ctxb@40MB (16MB)
  //   d_out: qbuf@0 (16MB) | kbuf@16MB (16MB)  -- dead before final GEMM overwrites d_out
  char* wsp = (char*)d_ws;
  unsigned short* xb    = (unsigned short*)(wsp);
  unsigned short* Wqkvb = (unsigned short*)(wsp + (size_t)(16u << 20));
  unsigned short* Wob   = (unsigned short*)(wsp + (size_t)(22u << 20));
  unsigned short* vbuf  = (unsigned short*)(wsp + (size_t)(24u << 20));
  unsigned short* ctxb  = (unsigned short*)(wsp + (size_t)(40u << 20));
  unsigned short* vtb   = (unsigned short*)(wsp);            // aliases xb (sequential reuse)
  unsigned short* qbuf  = (unsigned short*)d_out;
  unsigned short* kbuf  = (unsigned short*)d_out + (size_t)8388608;  // +16MB

  cvt_bf16_kernel<<<8388608 / 8 / 256, 256, 0, stream>>>(x, xb, 8388608 / 8, 0);
  cvt_bf16_kernel<<<3145728 / 8 / 256, 256, 0, stream>>>(Wqkv, Wqkvb, 3145728 / 8, 1);
  cvt_bf16_kernel<<<1048576 / 8 / 256, 256, 0, stream>>>(Wo, Wob, 1048576 / 8, 0);

  gemm_bt<0><<<(8192 / 128) * (3072 / 128), 256, 0, stream>>>(
      xb, Wqkvb, bqkv, qbuf, kbuf, vbuf, 8192, 3072, 1024, 3072 / 128);

  vtrans_kernel<<<2048, 256, 0, stream>>>(vbuf, vtb);

  attn_kernel<<<2048, 256, 0, stream>>>(qbuf, kbuf, vtb, pmask, ctxb);

  gemm_bt<1><<<(8192 / 128) * (1024 / 128), 256, 0, stream>>>(
      ctxb, Wob, bo, d_out, nullptr, nullptr, 8192, 1024, 1024, 1024 / 128);
}

// Round 4
// 146.658 us; speedup vs baseline: 1.3035x; 1.3035x over previous
//
#include <hip/hip_runtime.h>
#include <stdint.h>

typedef __attribute__((ext_vector_type(8))) short short8;
typedef __attribute__((ext_vector_type(4))) float f32x4;

__device__ __forceinline__ unsigned short f2bf(float f) {
  unsigned int u = __builtin_bit_cast(unsigned int, f);
  u += 0x7FFFu + ((u >> 16) & 1u);   // RNE
  return (unsigned short)(u >> 16);
}

#define GLD_LDS16(gp, lp) \
  __builtin_amdgcn_global_load_lds((const __attribute__((address_space(1))) void*)(gp), \
                                   (__attribute__((address_space(3))) void*)(lp), 16, 0, 0)

// ---------------- fused fp32 -> bf16 convert for x / Wqkv (q-rows pre-scaled) / Wo ------
__global__ __launch_bounds__(256) void cvt_all_kernel(
    const float* __restrict__ x, const float* __restrict__ Wqkv, const float* __restrict__ Wo,
    unsigned short* __restrict__ xb, unsigned short* __restrict__ Wqkvb,
    unsigned short* __restrict__ Wob) {
  int i = blockIdx.x * 256 + threadIdx.x;          // indexes 8-float chunks
  const float* src; unsigned short* dst; int local; float scale = 1.0f;
  if (i < 1048576) { src = x; dst = xb; local = i; }
  else if (i < 1048576 + 393216) {
    local = i - 1048576; src = Wqkv; dst = Wqkvb;
    int row = (local * 8) >> 10;                   // K = 1024 per row
    if (((row >> 6) % 3) == 0) scale = 0.125f;     // q rows: fold 1/sqrt(64), exact pow2
  } else { local = i - 1441792; src = Wo; dst = Wob; }
  const float4* s4 = (const float4*)src;
  float4 a = s4[local * 2], b = s4[local * 2 + 1];
  uint4 o;
  o.x = (unsigned)f2bf(a.x * scale) | ((unsigned)f2bf(a.y * scale) << 16);
  o.y = (unsigned)f2bf(a.z * scale) | ((unsigned)f2bf(a.w * scale) << 16);
  o.z = (unsigned)f2bf(b.x * scale) | ((unsigned)f2bf(b.y * scale) << 16);
  o.w = (unsigned)f2bf(b.z * scale) | ((unsigned)f2bf(b.w * scale) << 16);
  *(uint4*)(dst + (size_t)local * 8) = o;
}

// ---------------- 128x128-tile bf16 GEMM, C = A @ B^T (+bias), m97 structure ----------
// EPI 0: scatter q/k as [B][H][S][64], v TRANSPOSED as [B][H][64][S]   EPI 1: fp32 [M][N]
template<int EPI>
__global__ __launch_bounds__(256, 2) void gemm_bt(
    const unsigned short* __restrict__ A, const unsigned short* __restrict__ Bw,
    const float* __restrict__ bias, void* o0, void* o1, void* o2,
    int M, int N, int K, int nbc)
{
  __shared__ __align__(16) unsigned short Asm[128 * 64];
  __shared__ __align__(16) unsigned short Bsm[128 * 64];
  int bid = blockIdx.x;
  int bc = bid % nbc, br = bid / nbc;
  int tid = threadIdx.x;
  int lane = tid & 63, w = tid >> 6;
  int l16 = lane & 15, g = lane >> 4;
  int wr = w >> 1, wc = w & 1;
  f32x4 acc[4][4];
  #pragma unroll
  for (int i = 0; i < 4; i++)
    #pragma unroll
    for (int j = 0; j < 4; j++) acc[i][j] = (f32x4){0.f, 0.f, 0.f, 0.f};

  const int nkt = K >> 6;
  for (int kt = 0; kt < nkt; ++kt) {
    __syncthreads();
    #pragma unroll
    for (int r = 0; r < 4; ++r) {
      int idx = tid + 256 * r;            // lane-contiguous per wave (gload_lds linear dest)
      int row = idx >> 3, s = idx & 7;
      int gofs = ((s ^ (row & 7)) << 3) + (kt << 6);   // pre-swizzled global source
      GLD_LDS16(A + (size_t)(br * 128 + row) * K + gofs, &Asm[idx << 3]);
      GLD_LDS16(Bw + (size_t)(bc * 128 + row) * K + gofs, &Bsm[idx << 3]);
    }
    __syncthreads();
    #pragma unroll
    for (int kk = 0; kk < 2; ++kk) {
      short8 af[4], bf[4];
      #pragma unroll
      for (int i = 0; i < 4; i++) {
        int rowa = wr * 64 + i * 16 + l16;
        af[i] = *(const short8*)&Asm[(rowa << 6) + ((((kk << 2) + g) ^ (rowa & 7)) << 3)];
        int rowb = wc * 64 + i * 16 + l16;
        bf[i] = *(const short8*)&Bsm[(rowb << 6) + ((((kk << 2) + g) ^ (rowb & 7)) << 3)];
      }
      #pragma unroll
      for (int i = 0; i < 4; i++)
        #pragma unroll
        for (int j = 0; j < 4; j++)
          acc[i][j] = __builtin_amdgcn_mfma_f32_16x16x32_bf16(af[i], bf[j], acc[i][j], 0, 0, 0);
    }
  }
  // epilogue: D row = g*4+jj, col = l16 (m89-verified layout)
  #pragma unroll
  for (int i = 0; i < 4; i++) {
    #pragma unroll
    for (int j = 0; j < 4; j++) {
      int n = bc * 128 + wc * 64 + j * 16 + l16;
      int m0 = br * 128 + wr * 64 + i * 16 + g * 4;
      if (EPI == 0) {
        int t = (n >> 6) % 3;
        int hh = n / 192, e = n & 63;
        float bval = bias[n]; if (t == 0) bval *= 0.125f;
        int bb = m0 >> 12, s0 = m0 & 4095;          // S = 4096; m0 4-aligned, no b-straddle
        if (t == 2) {                               // v: transposed [bh][e][S], b64-packed
          unsigned short p0 = f2bf(acc[i][j][0] + bval);
          unsigned short p1 = f2bf(acc[i][j][1] + bval);
          unsigned short p2 = f2bf(acc[i][j][2] + bval);
          unsigned short p3 = f2bf(acc[i][j][3] + bval);
          uint2 pk;
          pk.x = (unsigned)p0 | ((unsigned)p1 << 16);
          pk.y = (unsigned)p2 | ((unsigned)p3 << 16);
          unsigned short* vt = (unsigned short*)o2;
          *(uint2*)&vt[(((size_t)(bb * 16 + hh) * 64 + e) << 12) + s0] = pk;
        } else {
          unsigned short* dst = (unsigned short*)(t == 0 ? o0 : o1);
          #pragma unroll
          for (int jj = 0; jj < 4; jj++)
            dst[((((size_t)(bb * 16 + hh) << 12) + s0 + jj) << 6) + e] = f2bf(acc[i][j][jj] + bval);
        }
      } else {
        float* o = (float*)o0;
        float bval = bias[n];
        #pragma unroll
        for (int jj = 0; jj < 4; jj++)
          o[(size_t)(m0 + jj) * N + n] = acc[i][j][jj] + bval;
      }
    }
  }
}

// ---------------- banded flash attention (no-max softmax, deferred denominator) --------
// grid: (S/64) * B*H blocks; 4 waves/block, wave owns 16 query rows.
// K staged [key][d], V^T staged [d][key], both via global_load_lds, double-buffered.
__global__ __launch_bounds__(256, 4) void attn_kernel(
    const unsigned short* __restrict__ qb, const unsigned short* __restrict__ kb,
    const unsigned short* __restrict__ vtb, const int* __restrict__ pmask,
    unsigned short* __restrict__ ctxb)
{
  const int S = 4096, HD = 64, WIN = 256;
  const float NEG = -1e38f;
  __shared__ __align__(16) unsigned short Ks[2][64 * 64];
  __shared__ __align__(16) unsigned short Vts[2][64 * 64];
  __shared__ __align__(16) unsigned short Ps[4][16 * 64];   // XOR-swizzled, no pad (40960B total)

  int bid0 = blockIdx.x;
  int bid = (bid0 & 7) * (gridDim.x >> 3) + (bid0 >> 3);   // XCD swizzle: 4 heads per XCD L2
  int qt = bid & 63;           // S/64 tiles
  int bh = bid >> 6;
  int b = bh >> 4, h = bh & 15;

  const unsigned short* Q  = qb + (size_t)bh * S * HD;
  const unsigned short* Kg = kb + (size_t)bh * S * HD;
  const unsigned short* Vt = vtb + (size_t)bh * HD * S;
  const int* pmrow = pmask + (size_t)b * S;

  int tid = threadIdx.x;
  int lane = tid & 63, w = tid >> 6;
  int l16 = lane & 15, g = lane >> 4;

  int q0 = qt * 64;
  int qw = q0 + w * 16;

  short8 qf[2];
  #pragma unroll
  for (int hh = 0; hh < 2; ++hh)
    qf[hh] = *(const short8*)&Q[(size_t)(qw + l16) * HD + hh * 32 + g * 8];

  f32x4 ctx[4];
  #pragma unroll
  for (int dt = 0; dt < 4; ++dt) ctx[dt] = (f32x4){0.f, 0.f, 0.f, 0.f};
  float lrun[4] = {0.f, 0.f, 0.f, 0.f};   // per-lane partial denominators

  int kt0 = (q0 - WIN) >> 6; if (kt0 < 0) kt0 = 0;
  int kt1 = (q0 + 63 + WIN) >> 6; if (kt1 > 63) kt1 = 63;
  int nt = kt1 - kt0 + 1;

#define STAGE(BUF, KT) do {                                                       \
    int kb_ = (KT) * 64;                                                          \
    _Pragma("unroll")                                                             \
    for (int r_ = 0; r_ < 2; ++r_) {                                              \
      int idx_ = tid + 256 * r_;                                                  \
      int row_ = idx_ >> 3, s_ = idx_ & 7;                                        \
      int c_ = (s_ ^ (row_ & 7)) << 3;                                            \
      GLD_LDS16(Kg + (size_t)(kb_ + row_) * HD + c_, &Ks[BUF][idx_ << 3]);        \
      GLD_LDS16(Vt + (size_t)row_ * S + kb_ + c_, &Vts[BUF][idx_ << 3]);          \
    }                                                                             \
  } while (0)

  STAGE(0, kt0);
  asm volatile("s_waitcnt vmcnt(0)" ::: "memory");
  __syncthreads();

  int cur = 0;
  for (int it = 0; it < nt; ++it) {
    int kbase = (kt0 + it) * 64;
    if (it + 1 < nt) STAGE(cur ^ 1, kt0 + it + 1);

    // padding-mask bias, issued early so latency hides under QK^T
    float kbv[4];
    #pragma unroll
    for (int k4 = 0; k4 < 4; ++k4)
      kbv[k4] = (pmrow[kbase + k4 * 16 + l16] != 0) ? 0.f : NEG;

    // QK^T : S[q = g*4+jj][key = 16*k4 + l16]  (q pre-scaled by 1/8)
    f32x4 sc[4];
    __builtin_amdgcn_s_setprio(1);
    #pragma unroll
    for (int k4 = 0; k4 < 4; ++k4) {
      int krow = k4 * 16 + l16;
      f32x4 s = (f32x4){0.f, 0.f, 0.f, 0.f};
      short8 kf0 = *(const short8*)&Ks[cur][(krow << 6) + ((g ^ (l16 & 7)) << 3)];
      s = __builtin_amdgcn_mfma_f32_16x16x32_bf16(qf[0], kf0, s, 0, 0, 0);
      short8 kf1 = *(const short8*)&Ks[cur][(krow << 6) + (((4 + g) ^ (l16 & 7)) << 3)];
      s = __builtin_amdgcn_mfma_f32_16x16x32_bf16(qf[1], kf1, s, 0, 0, 0);
      sc[k4] = s;
    }
    __builtin_amdgcn_s_setprio(0);

    // mask -> exp (no max subtraction: scores bounded, fp32-safe; masked -> exp(NEG)=0)
    #pragma unroll
    for (int k4 = 0; k4 < 4; ++k4) {
      int kg = kbase + k4 * 16 + l16;
      #pragma unroll
      for (int jj = 0; jj < 4; ++jj) {
        int dq = kg - (qw + g * 4 + jj) + WIN;      // in [0, 2*WIN] iff in band
        float sv = sc[k4][jj] + kbv[k4];
        sv = ((unsigned)dq <= 2u * WIN) ? sv : NEG;
        float p = __expf(sv);
        lrun[jj] += p;
        // Ps XOR-swizzle: row = g*4+jj, col = k4*16+l16; blk = (col>>3)^(row&7)
        int row = g * 4 + jj, col = k4 * 16 + l16;
        Ps[w][(row << 6) + ((((col >> 3) ^ (row & 7)) << 3) | (col & 7))] = f2bf(p);
      }
    }

    asm volatile("s_waitcnt lgkmcnt(0)" ::: "memory");  // P writes visible wave-wide
    __builtin_amdgcn_sched_barrier(0);
    // PV : ctx[q][d] += P[16q x 64keys] @ Vt[64d x 64keys]
    short8 pf0 = *(const short8*)&Ps[w][(l16 << 6) + ((g ^ (l16 & 7)) << 3)];
    short8 pf1 = *(const short8*)&Ps[w][(l16 << 6) + (((4 + g) ^ (l16 & 7)) << 3)];
    __builtin_amdgcn_s_setprio(1);
    #pragma unroll
    for (int dt = 0; dt < 4; ++dt) {
      int drow = dt * 16 + l16;
      short8 vf0 = *(const short8*)&Vts[cur][(drow << 6) + ((g ^ (drow & 7)) << 3)];
      ctx[dt] = __builtin_amdgcn_mfma_f32_16x16x32_bf16(pf0, vf0, ctx[dt], 0, 0, 0);
      short8 vf1 = *(const short8*)&Vts[cur][(drow << 6) + (((4 + g) ^ (drow & 7)) << 3)];
      ctx[dt] = __builtin_amdgcn_mfma_f32_16x16x32_bf16(pf1, vf1, ctx[dt], 0, 0, 0);
    }
    __builtin_amdgcn_s_setprio(0);

    if (it + 1 < nt) {
      asm volatile("s_waitcnt vmcnt(0)" ::: "memory");  // next tile landed (issued pre-compute)
      __syncthreads();                                   // all waves done with cur
      cur ^= 1;
    }
  }
#undef STAGE

  // denominator reduce (once): sum lrun over the 16 key-lanes of each g-group
  #pragma unroll
  for (int jj = 0; jj < 4; ++jj) {
    float ps = lrun[jj];
    #pragma unroll
    for (int mk = 1; mk < 16; mk <<= 1) ps += __shfl_xor(ps, mk);
    lrun[jj] = ps;
  }

  // write ctx as bf16 in [B][S][H*64] (A-layout for the output GEMM)
  #pragma unroll
  for (int jj = 0; jj < 4; ++jj) {
    float rc = (lrun[jj] > 0.f) ? (1.f / lrun[jj]) : 0.f;
    int qrow = qw + g * 4 + jj;
    size_t base = ((size_t)b * S + qrow) * 1024 + h * 64;
    #pragma unroll
    for (int dt = 0; dt < 4; ++dt)
      ctxb[base + dt * 16 + l16] = f2bf(ctx[dt][jj] * rc);
  }
}

// ---------------- launch ----------------------------------------------------------------
extern "C" void kernel_launch(void* const* d_in, const int* in_sizes, int n_in,
                              void* d_out, int out_size, void* d_ws, size_t ws_size,
                              hipStream_t stream) {
  const float* x     = (const float*)d_in[0];
  const int*   pmask = (const int*)d_in[1];
  const float* Wqkv  = (const float*)d_in[2];
  const float* bqkv  = (const float*)d_in[3];
  const float* Wo    = (const float*)d_in[4];
  const float* bo    = (const float*)d_in[5];

  // Memory map (56MB of ws + d_out doubling as q/k scratch):
  //   ws:    xb@0 (16MB) | Wqkvb@16MB (6MB) | Wob@22MB (2MB) | vtb@24MB (16MB) | ctxb@40MB (16MB)
  //   d_out: qbuf@0 (16MB) | kbuf@16MB (16MB)  -- dead before final GEMM overwrites d_out
  char* wsp = (char*)d_ws;
  unsigned short* xb    = (unsigned short*)(wsp);
  unsigned short* Wqkvb = (unsigned short*)(wsp + (size_t)(16u << 20));
  unsigned short* Wob   = (unsigned short*)(wsp + (size_t)(22u << 20));
  unsigned short* vtb   = (unsigned short*)(wsp + (size_t)(24u << 20));
  unsigned short* ctxb  = (unsigned short*)(wsp + (size_t)(40u << 20));
  unsigned short* qbuf  = (unsigned short*)d_out;
  unsigned short* kbuf  = (unsigned short*)d_out + (size_t)8388608;  // +16MB

  cvt_all_kernel<<<6144, 256, 0, stream>>>(x, Wqkv, Wo, xb, Wqkvb, Wob);

  gemm_bt<0><<<(8192 / 128) * (3072 / 128), 256, 0, stream>>>(
      xb, Wqkvb, bqkv, qbuf, kbuf, vtb, 8192, 3072, 1024, 3072 / 128);

  attn_kernel<<<2048, 256, 0, stream>>>(qbuf, kbuf, vtb, pmask, ctxb);

  gemm_bt<1><<<(8192 / 128) * (1024 / 128), 256, 0, stream>>>(
      ctxb, Wob, bo, d_out, nullptr, nullptr, 8192, 1024, 1024, 1024 / 128);
}